// Round 14
// baseline (631.693 us; speedup 1.0000x reference)
//
#include <hip/hip_runtime.h>

#define DEV static __device__ __forceinline__

// ---------------------------------------------------------------- encoder ---

struct EncW {
  const float* cw[4]; const float* cb[4]; const float* g[4]; const float* bt[4];
  const float* rw[4]; const float* rb[4]; const float* rg[4]; const float* rbt[4];
};

// act layout: [c][t*22+v], stride 220 floats, 64 rows. S = 4840-float scratch.
// pp-fast task mapping (og = tid/55). R13 result: barrier merge (33->28) was
// NEUTRAL -> enc is NOT barrier-bound; stall = intra-phase latency + racc
// spill (WRITE_SIZE 57MB vs 11.3MB true output). R14: L1 fused layer kills
// the cross-phase racc for L1 via weight pre-scaling + x-copy (below).

// L1-only fused layer (3->64): BN scales folded into weights, R-mix fused
// into C-mix as a 6-channel mix over [y(rows 0..2) | x-copy(rows 61..63)].
// No 32-float racc held across T/Sp. 5 barriers (was 6).
DEV void gcn_l1_fused(int tid,
    const float* __restrict__ cw, const float* __restrict__ cb,
    const float* __restrict__ gg, const float* __restrict__ bt,
    const float* __restrict__ rw, const float* __restrict__ rb,
    const float* __restrict__ rg, const float* __restrict__ rbt,
    const float* __restrict__ TmL, const float* __restrict__ AL, float preL,
    float* __restrict__ act, float* __restrict__ S, float* __restrict__ badd)
{
  const float inv = 0.99999499987f;           // 1/sqrt(1+1e-5)
  // ---- ph1: stage W2' = [cw*cm | rw*rm] (6x64) + TmT (at S+384) +
  //           combined bias + copy x rows 0..2 -> rows 61..63 ----
  for (int idx = tid; idx < 384 + 2200; idx += 512) {
    if (idx < 384) {
      int c = idx / 64, o = idx % 64;
      float w;
      if (c < 3) w = cw[o * 3 + c] * (gg[o] * inv);
      else       w = rw[o * 3 + (c - 3)] * (rg[o] * inv);
      S[idx] = w;
    } else {
      int j = idx - 384;                 // j = (t*10+q)*22 + v
      int tq = j / 22, v = j % 22;
      S[idx] = TmL[v * 100 + tq];
    }
  }
  for (int idx = tid; idx < 64; idx += 512) {
    float cm = gg[idx] * inv, rm = rg[idx] * inv;
    badd[idx] = (cb[idx] * cm + bt[idx]) + (rb[idx] * rm + rbt[idx]);
  }
  for (int i = tid; i < 660; i += 512) act[13420 + i] = act[i];  // x-copy
  __syncthreads();

  // ---- ph2: T-mix rows 0..2 (TmT at S+384) || stage A -> act rows 3..25 ----
  for (int idx = tid; idx < 33; idx += 512) {
    int v2 = idx % 11, c = idx / 11;
    float* base = act + c * 220 + v2 * 2;
    float xin[10][2];
    #pragma unroll
    for (int t = 0; t < 10; ++t) { xin[t][0] = base[t*22]; xin[t][1] = base[t*22+1]; }
    float ya[10][2];
    #pragma unroll
    for (int q = 0; q < 10; ++q) { ya[q][0] = 0.f; ya[q][1] = 0.f; }
    #pragma unroll
    for (int t = 0; t < 10; ++t) {
      const float* tm = S + 384 + t * 220 + v2 * 2;
      #pragma unroll
      for (int q = 0; q < 10; ++q) {
        ya[q][0] += tm[q*22]   * xin[t][0];
        ya[q][1] += tm[q*22+1] * xin[t][1];
      }
    }
    #pragma unroll
    for (int q = 0; q < 10; ++q) { base[q*22] = ya[q][0]; base[q*22+1] = ya[q][1]; }
  }
  for (int i = tid; i < 4840; i += 512) act[660 + i] = AL[i];
  __syncthreads();

  // ---- ph3: Sp-mix rows 0..2 (A from act+660) ----
  for (int idx = tid; idx < 30; idx += 512) {
    int t = idx % 10, c = idx / 10;
    float* row = act + c * 220 + t * 22;
    float yin[22];
    #pragma unroll
    for (int v = 0; v < 22; ++v) yin[v] = row[v];
    float za[22];
    #pragma unroll
    for (int w = 0; w < 22; ++w) za[w] = 0.f;
    #pragma unroll 2
    for (int v = 0; v < 22; ++v) {
      const float* ar = act + 660 + (t * 22 + v) * 22;
      float y0 = yin[v];
      #pragma unroll
      for (int w = 0; w < 22; ++w) za[w] += y0 * ar[w];
    }
    #pragma unroll
    for (int w = 0; w < 22; ++w) row[w] = za[w];
  }
  __syncthreads();

  // ---- ph4: fused 6-channel mix -> acc[32] (rows 0,1,2,61,62,63) ----
  float acc[32];
  const int og = tid / 55, pp = tid % 55;
  if (tid < 440) {
    #pragma unroll
    for (int k = 0; k < 32; ++k) acc[k] = 0.f;
    #pragma unroll
    for (int c = 0; c < 6; ++c) {
      const int cc = (c < 3) ? c : (58 + c);      // 0,1,2,61,62,63
      const float* wr = S + c * 64 + og * 8;
      float4 av = *(const float4*)(act + cc * 220 + pp * 4);
      float4 w0 = *(const float4*)(wr);
      float4 w1 = *(const float4*)(wr + 4);
      float wv[8] = {w0.x,w0.y,w0.z,w0.w,w1.x,w1.y,w1.z,w1.w};
      #pragma unroll
      for (int o = 0; o < 8; ++o) {
        acc[o*4+0] += wv[o]*av.x; acc[o*4+1] += wv[o]*av.y;
        acc[o*4+2] += wv[o]*av.z; acc[o*4+3] += wv[o]*av.w;
      }
    }
  }
  __syncthreads();   // all reads of act complete before overwrite

  // ---- ph5: write (scales already folded; + combined bias; PReLU) ----
  if (tid < 440) {
    #pragma unroll
    for (int o = 0; o < 8; ++o) {
      const float a = badd[og * 8 + o];
      #pragma unroll
      for (int k = 0; k < 4; ++k) {
        float y = acc[o*4+k] + a;
        act[(og*8+o)*220 + pp*4 + k] = (y >= 0.f) ? y : preL * y;
      }
    }
  }
  __syncthreads();
}

// Original-order layer (T/Sp before channel mixes): used for L3 (32->64).
template<int CI, int CO, int OGRAN>
DEV void gcn_orig(int tid,
    const float* __restrict__ cw, const float* __restrict__ cb,
    const float* __restrict__ gg, const float* __restrict__ bt,
    const float* __restrict__ rw, const float* __restrict__ rb,
    const float* __restrict__ rg, const float* __restrict__ rbt,
    const float* __restrict__ TmL, const float* __restrict__ AL, float preL,
    float* __restrict__ act, float* __restrict__ S,
    float* __restrict__ rmul, float* __restrict__ radd,
    float* __restrict__ cmul, float* __restrict__ cadd)
{
  constexpr int COP8 = (CO + 7) & ~7;
  constexpr int NT = (CO / OGRAN) * 55;
  constexpr int RWN = CI * COP8;
  constexpr int AOFF = CI * 220;               // A staged in act rows CI..
  static_assert(RWN + 2200 <= 4840, "rw+Tm co-stage must fit in S");
  static_assert(AOFF + 4840 <= 14080, "A must fit in free act rows");
  const float inv = 0.99999499987f;           // 1/sqrt(1+1e-5)

  // ---- phase 1: stage rw^T (padded) + TmT (at S+RWN) + BN consts ----
  for (int idx = tid; idx < RWN + 2200; idx += 512) {
    if (idx < RWN) {
      int c = idx / COP8, o = idx % COP8;
      S[idx] = (o < CO) ? rw[o * CI + c] : 0.f;
    } else {
      int j = idx - RWN;
      int tq = j / 22, v = j % 22;
      S[idx] = TmL[v * 100 + tq];
    }
  }
  for (int idx = tid; idx < 64; idx += 512) {
    bool ok = idx < CO;
    float rm = ok ? rg[idx] * inv : 0.f;
    float cm = ok ? gg[idx] * inv : 0.f;
    rmul[idx] = rm;
    radd[idx] = ok ? rb[idx] * rm + rbt[idx] : 0.f;
    cmul[idx] = cm;
    cadd[idx] = ok ? cb[idx] * cm + bt[idx] : 0.f;
  }
  __syncthreads();

  // ---- phase 2: R-mix -> registers (BN applied) ----
  float racc[OGRAN * 4];
  const int og = tid / 55, pp = tid % 55;
  if (tid < NT) {
    #pragma unroll
    for (int k = 0; k < OGRAN * 4; ++k) racc[k] = 0.f;
    #pragma unroll 4
    for (int c = 0; c < CI; ++c) {
      const float* wr = S + c * COP8 + og * OGRAN;
      float4 av = *(const float4*)(act + c * 220 + pp * 4);
      float wv[OGRAN];
      if constexpr (OGRAN == 8) {
        float4 w0 = *(const float4*)(wr);
        float4 w1 = *(const float4*)(wr + 4);
        wv[0]=w0.x; wv[1]=w0.y; wv[2]=w0.z; wv[3]=w0.w;
        wv[4]=w1.x; wv[5]=w1.y; wv[6]=w1.z; wv[7]=w1.w;
      } else if constexpr (OGRAN == 4) {
        float4 w0 = *(const float4*)(wr);
        wv[0]=w0.x; wv[1]=w0.y; wv[2]=w0.z; wv[3]=w0.w;
      } else {
        wv[0] = wr[0];
      }
      #pragma unroll
      for (int o = 0; o < OGRAN; ++o) {
        racc[o*4+0] += wv[o]*av.x; racc[o*4+1] += wv[o]*av.y;
        racc[o*4+2] += wv[o]*av.z; racc[o*4+3] += wv[o]*av.w;
      }
    }
    #pragma unroll
    for (int o = 0; o < OGRAN; ++o) {
      float m = rmul[og * OGRAN + o], a = radd[og * OGRAN + o];
      #pragma unroll
      for (int k = 0; k < 4; ++k) racc[o*4+k] = racc[o*4+k]*m + a;
    }
  }
  __syncthreads();

  // ---- phase 3: T-mix (rows <CI) || stage A -> act[AOFF] || cw^T -> S[0,RWN)
  for (int idx = tid; idx < CI * 11; idx += 512) {
    int v2 = idx % 11, c = idx / 11;
    float* base = act + c * 220 + v2 * 2;
    float xin[10][2];
    #pragma unroll
    for (int t = 0; t < 10; ++t) { xin[t][0] = base[t*22]; xin[t][1] = base[t*22+1]; }
    float ya[10][2];
    #pragma unroll
    for (int q = 0; q < 10; ++q) { ya[q][0] = 0.f; ya[q][1] = 0.f; }
    #pragma unroll
    for (int t = 0; t < 10; ++t) {
      const float* tm = S + RWN + t * 220 + v2 * 2;
      #pragma unroll
      for (int q = 0; q < 10; ++q) {
        ya[q][0] += tm[q*22]   * xin[t][0];
        ya[q][1] += tm[q*22+1] * xin[t][1];
      }
    }
    #pragma unroll
    for (int q = 0; q < 10; ++q) { base[q*22] = ya[q][0]; base[q*22+1] = ya[q][1]; }
  }
  for (int i = tid; i < 4840; i += 512) act[AOFF + i] = AL[i];
  for (int i = tid; i < RWN; i += 512) {
    int c = i / COP8, o = i % COP8;
    S[i] = (o < CO) ? cw[o * CI + c] : 0.f;
  }
  __syncthreads();

  // ---- phase 4: Sp-mix, in place (A from act[AOFF]) ----
  for (int idx = tid; idx < CI * 10; idx += 512) {
    int t = idx % 10, c = idx / 10;
    float* row = act + c * 220 + t * 22;
    float yin[22];
    #pragma unroll
    for (int v = 0; v < 22; ++v) yin[v] = row[v];
    float za[22];
    #pragma unroll
    for (int w = 0; w < 22; ++w) za[w] = 0.f;
    #pragma unroll 2
    for (int v = 0; v < 22; ++v) {
      const float* ar = act + AOFF + (t * 22 + v) * 22;
      float y0 = yin[v];
      #pragma unroll
      for (int w = 0; w < 22; ++w) za[w] += y0 * ar[w];
    }
    #pragma unroll
    for (int w = 0; w < 22; ++w) row[w] = za[w];
  }
  __syncthreads();

  // ---- phase 5: C-mix -> registers (cw from S) ----
  float cacc[OGRAN * 4];
  if (tid < NT) {
    #pragma unroll
    for (int k = 0; k < OGRAN * 4; ++k) cacc[k] = 0.f;
    #pragma unroll 4
    for (int c = 0; c < CI; ++c) {
      const float* wr = S + c * COP8 + og * OGRAN;
      float4 av = *(const float4*)(act + c * 220 + pp * 4);
      float wv[OGRAN];
      if constexpr (OGRAN == 8) {
        float4 w0 = *(const float4*)(wr);
        float4 w1 = *(const float4*)(wr + 4);
        wv[0]=w0.x; wv[1]=w0.y; wv[2]=w0.z; wv[3]=w0.w;
        wv[4]=w1.x; wv[5]=w1.y; wv[6]=w1.z; wv[7]=w1.w;
      } else if constexpr (OGRAN == 4) {
        float4 w0 = *(const float4*)(wr);
        wv[0]=w0.x; wv[1]=w0.y; wv[2]=w0.z; wv[3]=w0.w;
      } else {
        wv[0] = wr[0];
      }
      #pragma unroll
      for (int o = 0; o < OGRAN; ++o) {
        cacc[o*4+0] += wv[o]*av.x; cacc[o*4+1] += wv[o]*av.y;
        cacc[o*4+2] += wv[o]*av.z; cacc[o*4+3] += wv[o]*av.w;
      }
    }
  }
  __syncthreads();
  // ---- phase 6: write ----
  if (tid < NT) {
    #pragma unroll
    for (int o = 0; o < OGRAN; ++o) {
      float m = cmul[og * OGRAN + o], a = cadd[og * OGRAN + o];
      #pragma unroll
      for (int k = 0; k < 4; ++k) {
        float y = cacc[o*4+k]*m + a + racc[o*4+k];
        act[(og*OGRAN+o)*220 + pp*4 + k] = (y >= 0.f) ? y : preL * y;
      }
    }
  }
  __syncthreads();
}

// Reordered layer (channel mixes FIRST, then T/Sp on CO channels).
// AOFF >= 0: stage A into free act rows during T-phase (L4). AOFF < 0:
// act fully occupied (L2) -- separate A phase in S as before.
template<int CI, int CO, int OGRAN, int AOFF>
DEV void gcn_reord(int tid,
    const float* __restrict__ cw, const float* __restrict__ cb,
    const float* __restrict__ gg, const float* __restrict__ bt,
    const float* __restrict__ rw, const float* __restrict__ rb,
    const float* __restrict__ rg, const float* __restrict__ rbt,
    const float* __restrict__ TmL, const float* __restrict__ AL, float preL,
    float* __restrict__ act, float* __restrict__ S,
    float* __restrict__ rmul, float* __restrict__ radd,
    float* __restrict__ cmul, float* __restrict__ cadd)
{
  constexpr int CO2 = 2 * CO;
  constexpr int COP8 = (CO2 + 7) & ~7;
  constexpr int NT = (CO2 / OGRAN) * 55;
  constexpr int RWN = CI * COP8;
  static_assert(RWN <= 4840, "W2 must fit in S");
  static_assert(AOFF < 0 || AOFF + 4840 <= 14080, "A must fit in act");
  const float inv = 0.99999499987f;

  for (int idx = tid; idx < RWN; idx += 512) {
    int c = idx / COP8, o = idx % COP8;
    float w = 0.f;
    if (o < CO) w = cw[o * CI + c];
    else if (o < CO2) w = rw[(o - CO) * CI + c];
    S[idx] = w;
  }
  for (int idx = tid; idx < 64; idx += 512) {
    bool ok = idx < CO;
    float rm = ok ? rg[idx] * inv : 0.f;
    float cm = ok ? gg[idx] * inv : 0.f;
    rmul[idx] = rm;
    radd[idx] = ok ? rb[idx] * rm + rbt[idx] : 0.f;
    cmul[idx] = cm;
    cadd[idx] = ok ? cb[idx] * cm + bt[idx] : 0.f;
  }
  __syncthreads();

  float acc[OGRAN * 4];
  const int og = tid / 55, pp = tid % 55;
  if (tid < NT) {
    #pragma unroll
    for (int k = 0; k < OGRAN * 4; ++k) acc[k] = 0.f;
    #pragma unroll 4
    for (int c = 0; c < CI; ++c) {
      const float* wr = S + c * COP8 + og * OGRAN;
      float4 av = *(const float4*)(act + c * 220 + pp * 4);
      float wv[OGRAN];
      if constexpr (OGRAN == 8) {
        float4 w0 = *(const float4*)(wr);
        float4 w1 = *(const float4*)(wr + 4);
        wv[0]=w0.x; wv[1]=w0.y; wv[2]=w0.z; wv[3]=w0.w;
        wv[4]=w1.x; wv[5]=w1.y; wv[6]=w1.z; wv[7]=w1.w;
      } else if constexpr (OGRAN == 4) {
        float4 w0 = *(const float4*)(wr);
        wv[0]=w0.x; wv[1]=w0.y; wv[2]=w0.z; wv[3]=w0.w;
      } else {
        wv[0] = wr[0];
      }
      #pragma unroll
      for (int o = 0; o < OGRAN; ++o) {
        acc[o*4+0] += wv[o]*av.x; acc[o*4+1] += wv[o]*av.y;
        acc[o*4+2] += wv[o]*av.z; acc[o*4+3] += wv[o]*av.w;
      }
    }
  }
  __syncthreads();

  if (tid < NT) {
    #pragma unroll
    for (int o = 0; o < OGRAN; ++o) {
      const int oo = og * OGRAN + o;
      const bool isr = oo >= CO;
      const float m = isr ? rmul[oo - CO] : 1.f;
      const float a = isr ? radd[oo - CO] : 0.f;
      #pragma unroll
      for (int k = 0; k < 4; ++k)
        act[oo * 220 + pp * 4 + k] = acc[o*4+k] * m + a;
    }
  }
  for (int i = tid; i < 2200; i += 512) {
    int tq = i / 22, v = i % 22;
    S[i] = TmL[v * 100 + tq];
  }
  __syncthreads();

  // ---- T-mix on u rows || (AOFF>=0) stage A -> act[AOFF] ----
  for (int idx = tid; idx < CO * 11; idx += 512) {
    int v2 = idx % 11, c = idx / 11;
    float* base = act + c * 220 + v2 * 2;
    float xin[10][2];
    #pragma unroll
    for (int t = 0; t < 10; ++t) { xin[t][0] = base[t*22]; xin[t][1] = base[t*22+1]; }
    float ya[10][2];
    #pragma unroll
    for (int q = 0; q < 10; ++q) { ya[q][0] = 0.f; ya[q][1] = 0.f; }
    #pragma unroll
    for (int t = 0; t < 10; ++t) {
      const float* tm = S + t * 220 + v2 * 2;
      #pragma unroll
      for (int q = 0; q < 10; ++q) {
        ya[q][0] += tm[q*22]   * xin[t][0];
        ya[q][1] += tm[q*22+1] * xin[t][1];
      }
    }
    #pragma unroll
    for (int q = 0; q < 10; ++q) { base[q*22] = ya[q][0]; base[q*22+1] = ya[q][1]; }
  }
  if constexpr (AOFF >= 0) {
    for (int i = tid; i < 4840; i += 512) act[AOFF + i] = AL[i];
  }
  __syncthreads();

  if constexpr (AOFF < 0) {
    for (int idx = tid; idx < 4840; idx += 512) S[idx] = AL[idx];
    __syncthreads();
  }

  // ---- Sp-mix on u rows ----
  {
    const float* Abase = (AOFF >= 0) ? (act + AOFF) : S;
    for (int idx = tid; idx < CO * 10; idx += 512) {
      int t = idx % 10, c = idx / 10;
      float* row = act + c * 220 + t * 22;
      float yin[22];
      #pragma unroll
      for (int v = 0; v < 22; ++v) yin[v] = row[v];
      float za[22];
      #pragma unroll
      for (int w = 0; w < 22; ++w) za[w] = 0.f;
      #pragma unroll 2
      for (int v = 0; v < 22; ++v) {
        const float* ar = Abase + (t * 22 + v) * 22;
        float y0 = yin[v];
        #pragma unroll
        for (int w = 0; w < 22; ++w) za[w] += y0 * ar[w];
      }
      #pragma unroll
      for (int w = 0; w < 22; ++w) row[w] = za[w];
    }
  }
  __syncthreads();

  for (int idx = tid; idx < CO * 220; idx += 512) {
    int o = idx / 220, p = idx % 220;
    float y = act[o * 220 + p] * cmul[o] + cadd[o] + act[(CO + o) * 220 + p];
    act[o * 220 + p] = (y >= 0.f) ? y : preL * y;
  }
  __syncthreads();
}

__global__ __launch_bounds__(512, 4)
void enc_kernel(const float* __restrict__ x, const float* __restrict__ A,
                const float* __restrict__ Tm, const float* __restrict__ pre, EncW W,
                const float* __restrict__ qkvT, const float* __restrict__ qkv_b,
                float* __restrict__ h0_ws, float* __restrict__ k_ws,
                float* __restrict__ v_ws)
{
  __shared__ __align__(16) float act[64 * 220];   // 56320 B
  __shared__ __align__(16) float S[4840];         // 19360 B (W/Tm/A mux)
  __shared__ float rmul[64], radd[64], cmul[64], cadd[64];  // 1024 B

  const int tid = threadIdx.x;
  const int b = blockIdx.x;

  for (int idx = tid; idx < 660; idx += 512) {
    int c = idx / 220, r = idx % 220, t = r / 22, v = r % 22;
    act[c * 220 + t * 22 + v] = x[(((size_t)b * 10 + t) * 22 + v) * 3 + c];
  }
  float p0 = pre[0], p1 = pre[1], p2 = pre[2], p3 = pre[3];

  gcn_l1_fused(tid, W.cw[0], W.cb[0], W.g[0], W.bt[0], W.rw[0], W.rb[0], W.rg[0], W.rbt[0],
               Tm, A, p0, act, S, cadd);
  gcn_reord<64, 32, 8, -1>(tid, W.cw[1], W.cb[1], W.g[1], W.bt[1], W.rw[1], W.rb[1], W.rg[1], W.rbt[1],
                     Tm + 2200, A + 4840, p1, act, S, rmul, radd, cmul, cadd);
  gcn_orig<32, 64, 8>(tid, W.cw[2], W.cb[2], W.g[2], W.bt[2], W.rw[2], W.rb[2], W.rg[2], W.rbt[2],
                     Tm + 4400, A + 9680, p2, act, S, rmul, radd, cmul, cadd);
  gcn_reord<64, 3, 1, 6 * 220>(tid, W.cw[3], W.cb[3], W.g[3], W.bt[3], W.rw[3], W.rb[3], W.rg[3], W.rbt[3],
                     Tm + 6600, A + 14520, p3, act, S, rmul, radd, cmul, cadd);

  float* encD = act + 3 * 220;
  for (int idx = tid; idx < 660; idx += 512) {
    int t = idx / 66, d = idx % 66, v = d / 3, c = d % 3;
    float val = act[c * 220 + t * 22 + v];
    encD[idx] = val;
    if (t == 9) h0_ws[(size_t)b * 66 + d] = val;
  }
  __syncthreads();

  for (int idx = tid; idx < 1320; idx += 512) {
    const int t = idx / 132, dd = idx % 132;
    const int row = 66 + dd;
    const float* wp = qkvT + row;        // qkvT[e*198+row]
    const float* ep = encD + t * 66;
    float acc = 0.f;
    #pragma unroll 6
    for (int e = 0; e < 66; ++e) acc += wp[e * 198] * ep[e];
    acc += qkv_b[row];
    const int half = dd / 66, d = dd - half * 66;
    float* dst = half ? v_ws : k_ws;
    dst[(size_t)b * 660 + t * 66 + d] = acc;
  }
}

// ------------------------- prep: transposes + folds (all f32) ---------------

__global__ __launch_bounds__(512)
void prep_kernel(const float* __restrict__ qkv_w, const float* __restrict__ ow,
                 const float* __restrict__ ob, const float* __restrict__ lw,
                 const float* __restrict__ gru_wi, const float* __restrict__ gru_wh,
                 float* __restrict__ qkvT, float* __restrict__ wqD,
                 float* __restrict__ lwAT, float* __restrict__ MT,
                 float* __restrict__ cb2, float* __restrict__ wT_g)
{
  int idx = blockIdx.x * 512 + threadIdx.x;
  if (idx < 13068) {                 // qkvT[e*198+j] = qkv_w[j*66+e]
    int e = idx / 198, j = idx % 198;
    qkvT[idx] = qkv_w[j * 66 + e];
    return;
  }
  int i1 = idx - 13068;
  if (i1 < 4356) {                   // wqD[e*66+d] = qkv_w[d*66+e]
    int e = i1 / 66, d = i1 % 66;
    wqD[i1] = qkv_w[d * 66 + e];
    return;
  }
  int i2 = i1 - 4356;
  if (i2 < 4356) {                   // lwAT[e*66+d] = lw[d*132+e]
    int e = i2 / 66, d = i2 % 66;
    lwAT[i2] = lw[d * 132 + e];
    return;
  }
  int i3 = i2 - 4356;
  if (i3 < 4356) {                   // MT[e*66+d] = sum_f lwB[d][f]*ow[f][e]
    int e = i3 / 66, d = i3 % 66;
    const float* lrow = lw + d * 132 + 66;
    float acc = 0.f;
    for (int f = 0; f < 66; ++f) acc += lrow[f] * ow[f * 66 + e];
    MT[i3] = acc;
    return;
  }
  int i4 = i3 - 4356;
  if (i4 < 66) {                     // cb2[d] = lwB[d] @ ob
    const float* lrow = lw + i4 * 132 + 66;
    float acc = 0.f;
    for (int f = 0; f < 66; ++f) acc += lrow[f] * ob[f];
    cb2[i4] = acc;
    return;
  }
  int i5 = i4 - 66;
  if (i5 < 26136) {                  // wT_g[e*396+jm]: jm<198 wi, else wh
    int e = i5 / 396, jm = i5 % 396;
    wT_g[i5] = (jm < 198) ? gru_wi[jm * 66 + e] : gru_wh[(jm - 198) * 66 + e];
  }
}

// ---------------------------------------------------------------- decoder ---
// EXACT R10 champion decoder (298us, FETCH ~7MB). R11 lesson (3rd instance
// of the same wall): dec restructures that raise per-thread load-in-flight
// count (wide unrolls, float4 weight streams, per-thread arrays) spill at
// the allocator's fixed 64-VGPR target -> GB-scale scratch traffic. Keep
// short unrolls (11), scalar weight loads, <=~40 live floats per thread.
// (R3: don't shrink R. R9: don't stream lwAT/MT per-step from global.)

__global__ __launch_bounds__(512, 4)
void dec_kernel(const float* __restrict__ x, const float* __restrict__ h0_ws,
                const float* __restrict__ k_ws, const float* __restrict__ v_ws,
                const float* __restrict__ wT_g,
                const float* __restrict__ gru_bi, const float* __restrict__ gru_bh,
                const float* __restrict__ wqD, const float* __restrict__ qkv_b,
                const float* __restrict__ lwAT, const float* __restrict__ MT,
                const float* __restrict__ cb2, const float* __restrict__ lb,
                float* __restrict__ outp)
{
  __shared__ __align__(16) float kpS[7920];      // 31680 B  (r,h,t) x e
  __shared__ __align__(16) float lwAS[4356];     // 17424 B
  __shared__ __align__(16) float MS[4356];       // 17424 B
  __shared__ __align__(16) float G[396 * 4];     //  6336 B
  __shared__ __align__(16) float tpT[264], hsT[264], cxT[264];  // 3168 B
  __shared__ float attnS[120];                   //   480 B (raw scores)
  __shared__ float kbS[120];                     //   480 B
  __shared__ float biS[198], bhS[198], lbS[66];  //  1848 B
  // total ~78.9 KB -> 2 blocks/CU

  const int tid = threadIdx.x;
  const int b0 = blockIdx.x * 4;
  const float qscale = 1.0f / sqrtf(22.0f);

  for (int idx = tid; idx < 4356; idx += 512) {
    lwAS[idx] = lwAT[idx]; MS[idx] = MT[idx];
  }
  for (int idx = tid; idx < 198; idx += 512) { biS[idx] = gru_bi[idx]; bhS[idx] = gru_bh[idx]; }
  for (int idx = tid; idx < 66; idx += 512)  { lbS[idx] = lb[idx] + cb2[idx]; }
  for (int idx = tid; idx < 264; idx += 512) {
    int d = idx >> 2, r = idx & 3;
    hsT[d * 4 + r] = h0_ws[(size_t)(b0 + r) * 66 + d];
    tpT[d * 4 + r] = x[(size_t)(b0 + r) * 660 + 594 + d];
  }
  // kp precompute: kp[r,h,t,e] = scale*sum_j wq[h*22+j,e]*k[r,t,h*22+j]
  for (int idx = tid; idx < 7920; idx += 512) {
    const int g = idx / 66, e = idx % 66;
    const int r = g / 30, rem = g % 30, h = rem / 10, t = rem % 10;
    const float* wq = wqD + e * 66 + h * 22;
    const float* kv = k_ws + (size_t)(b0 + r) * 660 + t * 66 + h * 22;
    float acc = 0.f;
    #pragma unroll
    for (int j = 0; j < 22; ++j) acc += wq[j] * kv[j];
    kpS[idx] = acc * qscale;
  }
  for (int idx = tid; idx < 120; idx += 512) {
    const int r = idx / 30, rem = idx % 30, h = rem / 10, t = rem % 10;
    const float* kv = k_ws + (size_t)(b0 + r) * 660 + t * 66 + h * 22;
    float acc = 0.f;
    #pragma unroll
    for (int j = 0; j < 22; ++j) acc += qkv_b[h * 22 + j] * kv[j];
    kbS[idx] = acc * qscale;
  }
  __syncthreads();

  for (int s = 0; s < 25; ++s) {
    // P1: G[jm] = act @ w_jm + bias; 198 threads x 2 columns sharing one
    // activation stream. tid<99: wi cols (tid, tid+99), src tpT.
    // tid in [99,198): wh cols (tid+99, tid+198), src hsT.
    if (tid < 198) {
      const bool lo = tid < 99;
      const int j0 = lo ? tid : (tid + 99);
      const int j1 = j0 + 99;
      const float* base = lo ? tpT : hsT;
      const float* w0 = wT_g + j0;
      const float* w1 = wT_g + j1;
      float a0 = 0.f, a1 = 0.f, a2 = 0.f, a3 = 0.f;
      float c0 = 0.f, c1 = 0.f, c2 = 0.f, c3 = 0.f;
      #pragma unroll 11
      for (int e = 0; e < 66; ++e) {
        float4 av = *(const float4*)(base + e * 4);
        const float wa = w0[e * 396];
        const float wb = w1[e * 396];
        a0 += wa * av.x; a1 += wa * av.y; a2 += wa * av.z; a3 += wa * av.w;
        c0 += wb * av.x; c1 += wb * av.y; c2 += wb * av.z; c3 += wb * av.w;
      }
      const float bias0 = lo ? biS[j0] : bhS[j0 - 198];
      const float bias1 = lo ? biS[j1] : bhS[j1 - 198];
      *(float4*)(G + j0 * 4) = make_float4(a0 + bias0, a1 + bias0, a2 + bias0, a3 + bias0);
      *(float4*)(G + j1 * 4) = make_float4(c0 + bias1, c1 + bias1, c2 + bias1, c3 + bias1);
    }
    __syncthreads();

    // P2: GRU gates -> hs
    if (tid < 264) {
      int d = tid >> 2, r = tid & 3;
      float ir = G[d * 4 + r]         + G[(198 + d) * 4 + r];
      float iz = G[(66 + d) * 4 + r]  + G[(264 + d) * 4 + r];
      float nx = G[(132 + d) * 4 + r];
      float hn = G[(330 + d) * 4 + r];
      float rg = 1.f / (1.f + __expf(-ir));
      float zg = 1.f / (1.f + __expf(-iz));
      float t2 = __expf(2.f * (nx + rg * hn));
      float ng = 1.f - 2.f / (t2 + 1.f);        // tanh, overflow-safe
      float h = hsT[d * 4 + r];
      hsT[d * 4 + r] = (1.f - zg) * ng + zg * h;
    }
    __syncthreads();

    // P4a: raw scores via kp (480 lanes: 4-way e-split + shfl combine)
    if (tid < 480) {
      const int g = tid >> 2, q4 = tid & 3;
      const int r = g / 30;
      const int e0 = q4 * 17;
      const int e1 = (q4 == 3) ? 66 : e0 + 17;
      const float* kpr = kpS + g * 66;
      float acc = 0.f;
      for (int e = e0; e < e1; ++e) acc += hsT[e * 4 + r] * kpr[e];
      acc += __shfl_xor(acc, 1);
      acc += __shfl_xor(acc, 2);
      if (q4 == 0) attnS[g] = acc + kbS[g];
    }
    __syncthreads();

    // P5: per-thread softmax + ctx = (sum p*v)/sum p (v from global, L2-hot)
    if (tid < 264) {
      int r = tid / 66, d = tid % 66, h = d / 22;
      const float* sp = attnS + (r * 3 + h) * 10;
      float sc[10];
      float mx = sp[0];
      #pragma unroll
      for (int t = 1; t < 10; ++t) { sc[t] = sp[t]; mx = fmaxf(mx, sp[t]); }
      sc[0] = sp[0];
      float sum = 0.f;
      #pragma unroll
      for (int t = 0; t < 10; ++t) { float e = __expf(sc[t] - mx); sc[t] = e; sum += e; }
      const float* vp = v_ws + (size_t)(b0 + r) * 660 + d;
      float acc = 0.f;
      #pragma unroll
      for (int t = 0; t < 10; ++t) acc += sc[t] * vp[t * 66];
      cxT[d * 4 + r] = acc / sum;
    }
    __syncthreads();

    // P7: thread (d, q=tid&3) computes partials for ALL 4 rows over e-chunk
    // q (4 LDS insts / 4 outputs); 4-lane shfl_xor combine; thread q keeps r=q.
    if (tid < 264) {
      const int d = tid >> 2, q = tid & 3;
      const int e0 = q * 17;
      const int e1 = (q == 3) ? 66 : e0 + 17;
      float x0 = 0.f, x1 = 0.f, x2 = 0.f, x3 = 0.f;
      for (int e = e0; e < e1; ++e) {
        const float wa = lwAS[e * 66 + d];
        const float wm = MS[e * 66 + d];
        const float4 hv = *(const float4*)(hsT + e * 4);
        const float4 cv = *(const float4*)(cxT + e * 4);
        x0 += wa * hv.x + wm * cv.x;
        x1 += wa * hv.y + wm * cv.y;
        x2 += wa * hv.z + wm * cv.z;
        x3 += wa * hv.w + wm * cv.w;
      }
      x0 += __shfl_xor(x0, 1); x0 += __shfl_xor(x0, 2);
      x1 += __shfl_xor(x1, 1); x1 += __shfl_xor(x1, 2);
      x2 += __shfl_xor(x2, 1); x2 += __shfl_xor(x2, 2);
      x3 += __shfl_xor(x3, 1); x3 += __shfl_xor(x3, 2);
      const float val = (q == 0) ? x0 : (q == 1) ? x1 : (q == 2) ? x2 : x3;
      const float pred = val + lbS[d] + tpT[d * 4 + q];
      outp[((size_t)(b0 + q) * 25 + s) * 66 + d] = pred;
      tpT[d * 4 + q] = pred;
    }
    __syncthreads();
  }
}

// ----------------------------------------------------------------- launch ---

extern "C" void kernel_launch(void* const* d_in, const int* in_sizes, int n_in,
                              void* d_out, int out_size, void* d_ws, size_t ws_size,
                              hipStream_t stream) {
  (void)in_sizes; (void)n_in; (void)out_size; (void)ws_size;
  const float* x   = (const float*)d_in[0];
  const float* A   = (const float*)d_in[1];
  const float* Tm  = (const float*)d_in[2];
  const float* pre = (const float*)d_in[3];
  EncW W;
  for (int i = 0; i < 4; ++i) {
    W.cw[i]  = (const float*)d_in[4 + 8 * i + 0];
    W.cb[i]  = (const float*)d_in[4 + 8 * i + 1];
    W.g[i]   = (const float*)d_in[4 + 8 * i + 2];
    W.bt[i]  = (const float*)d_in[4 + 8 * i + 3];
    W.rw[i]  = (const float*)d_in[4 + 8 * i + 4];
    W.rb[i]  = (const float*)d_in[4 + 8 * i + 5];
    W.rg[i]  = (const float*)d_in[4 + 8 * i + 6];
    W.rbt[i] = (const float*)d_in[4 + 8 * i + 7];
  }
  const float* gru_wi = (const float*)d_in[36];
  const float* gru_wh = (const float*)d_in[37];
  const float* gru_bi = (const float*)d_in[38];
  const float* gru_bh = (const float*)d_in[39];
  const float* qkv_w  = (const float*)d_in[40];
  const float* qkv_b  = (const float*)d_in[41];
  const float* ow     = (const float*)d_in[42];
  const float* ob     = (const float*)d_in[43];
  const float* lw     = (const float*)d_in[44];
  const float* lb     = (const float*)d_in[45];

  float* wsf  = (float*)d_ws;
  float* h0   = wsf;                       // 2048*66
  float* kw   = h0 + 2048 * 66;            // 2048*660
  float* vw   = kw + 2048 * 660;           // 2048*660
  float* qkvT = vw + 2048 * 660;           // 13068
  float* wqD  = qkvT + 13068;              // 4356
  float* lwAT = wqD + 4356;                // 4356
  float* MT   = lwAT + 4356;               // 4356
  float* cb2  = MT + 4356;                 // 66
  float* wT_g = cb2 + 66;                  // 26136

  prep_kernel<<<103, 512, 0, stream>>>(qkv_w, ow, ob, lw, gru_wi, gru_wh,
                                       qkvT, wqD, lwAT, MT, cb2, wT_g);
  enc_kernel<<<2048, 512, 0, stream>>>(x, A, Tm, pre, W, qkvT, qkv_b, h0, kw, vw);
  dec_kernel<<<512, 512, 0, stream>>>(x, h0, kw, vw, wT_g, gru_bi, gru_bh,
                                      wqD, qkv_b, lwAT, MT, cb2, lb,
                                      (float*)d_out);
}

// Round 15
// 624.640 us; speedup vs baseline: 1.0113x; 1.0113x over previous
//
#include <hip/hip_runtime.h>

#define DEV static __device__ __forceinline__

// ---------------------------------------------------------------- encoder ---

struct EncW {
  const float* cw[4]; const float* cb[4]; const float* g[4]; const float* bt[4];
  const float* rw[4]; const float* rb[4]; const float* rg[4]; const float* rbt[4];
};

// act layout: [c][t*22+v], stride 220 floats, 64 rows. S = 4840-float scratch.
// pp-fast task mapping (og = tid/55). Final config (R14): fused L1 (BN folded
// into weights, R-mix merged into C-mix via x-copy), merged staging phases
// (A/cw staged during T-mix), R10 decoder. Session findings: enc is NOT
// barrier-bound (33->28 neutral) and NOT conflict-bound (1.8% of cycles);
// residual ~57% non-VALU time is intra-phase LDS latency. dec is latency-
// bound on its serial 25-step chain; all MLP-widening restructures spill at
// the allocator's fixed 64-VGPR target (R6/R9/R11).

// L1-only fused layer (3->64): BN scales folded into weights, R-mix fused
// into C-mix as a 6-channel mix over [y(rows 0..2) | x-copy(rows 61..63)].
DEV void gcn_l1_fused(int tid,
    const float* __restrict__ cw, const float* __restrict__ cb,
    const float* __restrict__ gg, const float* __restrict__ bt,
    const float* __restrict__ rw, const float* __restrict__ rb,
    const float* __restrict__ rg, const float* __restrict__ rbt,
    const float* __restrict__ TmL, const float* __restrict__ AL, float preL,
    float* __restrict__ act, float* __restrict__ S, float* __restrict__ badd)
{
  const float inv = 0.99999499987f;           // 1/sqrt(1+1e-5)
  // ---- ph1: stage W2' = [cw*cm | rw*rm] (6x64) + TmT (at S+384) +
  //           combined bias + copy x rows 0..2 -> rows 61..63 ----
  for (int idx = tid; idx < 384 + 2200; idx += 512) {
    if (idx < 384) {
      int c = idx / 64, o = idx % 64;
      float w;
      if (c < 3) w = cw[o * 3 + c] * (gg[o] * inv);
      else       w = rw[o * 3 + (c - 3)] * (rg[o] * inv);
      S[idx] = w;
    } else {
      int j = idx - 384;                 // j = (t*10+q)*22 + v
      int tq = j / 22, v = j % 22;
      S[idx] = TmL[v * 100 + tq];
    }
  }
  for (int idx = tid; idx < 64; idx += 512) {
    float cm = gg[idx] * inv, rm = rg[idx] * inv;
    badd[idx] = (cb[idx] * cm + bt[idx]) + (rb[idx] * rm + rbt[idx]);
  }
  for (int i = tid; i < 660; i += 512) act[13420 + i] = act[i];  // x-copy
  __syncthreads();

  // ---- ph2: T-mix rows 0..2 (TmT at S+384) || stage A -> act rows 3..25 ----
  for (int idx = tid; idx < 33; idx += 512) {
    int v2 = idx % 11, c = idx / 11;
    float* base = act + c * 220 + v2 * 2;
    float xin[10][2];
    #pragma unroll
    for (int t = 0; t < 10; ++t) { xin[t][0] = base[t*22]; xin[t][1] = base[t*22+1]; }
    float ya[10][2];
    #pragma unroll
    for (int q = 0; q < 10; ++q) { ya[q][0] = 0.f; ya[q][1] = 0.f; }
    #pragma unroll
    for (int t = 0; t < 10; ++t) {
      const float* tm = S + 384 + t * 220 + v2 * 2;
      #pragma unroll
      for (int q = 0; q < 10; ++q) {
        ya[q][0] += tm[q*22]   * xin[t][0];
        ya[q][1] += tm[q*22+1] * xin[t][1];
      }
    }
    #pragma unroll
    for (int q = 0; q < 10; ++q) { base[q*22] = ya[q][0]; base[q*22+1] = ya[q][1]; }
  }
  for (int i = tid; i < 4840; i += 512) act[660 + i] = AL[i];
  __syncthreads();

  // ---- ph3: Sp-mix rows 0..2 (A from act+660) ----
  for (int idx = tid; idx < 30; idx += 512) {
    int t = idx % 10, c = idx / 10;
    float* row = act + c * 220 + t * 22;
    float yin[22];
    #pragma unroll
    for (int v = 0; v < 22; ++v) yin[v] = row[v];
    float za[22];
    #pragma unroll
    for (int w = 0; w < 22; ++w) za[w] = 0.f;
    #pragma unroll 2
    for (int v = 0; v < 22; ++v) {
      const float* ar = act + 660 + (t * 22 + v) * 22;
      float y0 = yin[v];
      #pragma unroll
      for (int w = 0; w < 22; ++w) za[w] += y0 * ar[w];
    }
    #pragma unroll
    for (int w = 0; w < 22; ++w) row[w] = za[w];
  }
  __syncthreads();

  // ---- ph4: fused 6-channel mix -> acc[32] (rows 0,1,2,61,62,63) ----
  float acc[32];
  const int og = tid / 55, pp = tid % 55;
  if (tid < 440) {
    #pragma unroll
    for (int k = 0; k < 32; ++k) acc[k] = 0.f;
    #pragma unroll
    for (int c = 0; c < 6; ++c) {
      const int cc = (c < 3) ? c : (58 + c);      // 0,1,2,61,62,63
      const float* wr = S + c * 64 + og * 8;
      float4 av = *(const float4*)(act + cc * 220 + pp * 4);
      float4 w0 = *(const float4*)(wr);
      float4 w1 = *(const float4*)(wr + 4);
      float wv[8] = {w0.x,w0.y,w0.z,w0.w,w1.x,w1.y,w1.z,w1.w};
      #pragma unroll
      for (int o = 0; o < 8; ++o) {
        acc[o*4+0] += wv[o]*av.x; acc[o*4+1] += wv[o]*av.y;
        acc[o*4+2] += wv[o]*av.z; acc[o*4+3] += wv[o]*av.w;
      }
    }
  }
  __syncthreads();   // all reads of act complete before overwrite

  // ---- ph5: write (scales already folded; + combined bias; PReLU) ----
  if (tid < 440) {
    #pragma unroll
    for (int o = 0; o < 8; ++o) {
      const float a = badd[og * 8 + o];
      #pragma unroll
      for (int k = 0; k < 4; ++k) {
        float y = acc[o*4+k] + a;
        act[(og*8+o)*220 + pp*4 + k] = (y >= 0.f) ? y : preL * y;
      }
    }
  }
  __syncthreads();
}

// Original-order layer (T/Sp before channel mixes): used for L3 (32->64).
template<int CI, int CO, int OGRAN>
DEV void gcn_orig(int tid,
    const float* __restrict__ cw, const float* __restrict__ cb,
    const float* __restrict__ gg, const float* __restrict__ bt,
    const float* __restrict__ rw, const float* __restrict__ rb,
    const float* __restrict__ rg, const float* __restrict__ rbt,
    const float* __restrict__ TmL, const float* __restrict__ AL, float preL,
    float* __restrict__ act, float* __restrict__ S,
    float* __restrict__ rmul, float* __restrict__ radd,
    float* __restrict__ cmul, float* __restrict__ cadd)
{
  constexpr int COP8 = (CO + 7) & ~7;
  constexpr int NT = (CO / OGRAN) * 55;
  constexpr int RWN = CI * COP8;
  constexpr int AOFF = CI * 220;               // A staged in act rows CI..
  static_assert(RWN + 2200 <= 4840, "rw+Tm co-stage must fit in S");
  static_assert(AOFF + 4840 <= 14080, "A must fit in free act rows");
  const float inv = 0.99999499987f;           // 1/sqrt(1+1e-5)

  // ---- phase 1: stage rw^T (padded) + TmT (at S+RWN) + BN consts ----
  for (int idx = tid; idx < RWN + 2200; idx += 512) {
    if (idx < RWN) {
      int c = idx / COP8, o = idx % COP8;
      S[idx] = (o < CO) ? rw[o * CI + c] : 0.f;
    } else {
      int j = idx - RWN;
      int tq = j / 22, v = j % 22;
      S[idx] = TmL[v * 100 + tq];
    }
  }
  for (int idx = tid; idx < 64; idx += 512) {
    bool ok = idx < CO;
    float rm = ok ? rg[idx] * inv : 0.f;
    float cm = ok ? gg[idx] * inv : 0.f;
    rmul[idx] = rm;
    radd[idx] = ok ? rb[idx] * rm + rbt[idx] : 0.f;
    cmul[idx] = cm;
    cadd[idx] = ok ? cb[idx] * cm + bt[idx] : 0.f;
  }
  __syncthreads();

  // ---- phase 2: R-mix -> registers (BN applied) ----
  float racc[OGRAN * 4];
  const int og = tid / 55, pp = tid % 55;
  if (tid < NT) {
    #pragma unroll
    for (int k = 0; k < OGRAN * 4; ++k) racc[k] = 0.f;
    #pragma unroll 4
    for (int c = 0; c < CI; ++c) {
      const float* wr = S + c * COP8 + og * OGRAN;
      float4 av = *(const float4*)(act + c * 220 + pp * 4);
      float wv[OGRAN];
      if constexpr (OGRAN == 8) {
        float4 w0 = *(const float4*)(wr);
        float4 w1 = *(const float4*)(wr + 4);
        wv[0]=w0.x; wv[1]=w0.y; wv[2]=w0.z; wv[3]=w0.w;
        wv[4]=w1.x; wv[5]=w1.y; wv[6]=w1.z; wv[7]=w1.w;
      } else if constexpr (OGRAN == 4) {
        float4 w0 = *(const float4*)(wr);
        wv[0]=w0.x; wv[1]=w0.y; wv[2]=w0.z; wv[3]=w0.w;
      } else {
        wv[0] = wr[0];
      }
      #pragma unroll
      for (int o = 0; o < OGRAN; ++o) {
        racc[o*4+0] += wv[o]*av.x; racc[o*4+1] += wv[o]*av.y;
        racc[o*4+2] += wv[o]*av.z; racc[o*4+3] += wv[o]*av.w;
      }
    }
    #pragma unroll
    for (int o = 0; o < OGRAN; ++o) {
      float m = rmul[og * OGRAN + o], a = radd[og * OGRAN + o];
      #pragma unroll
      for (int k = 0; k < 4; ++k) racc[o*4+k] = racc[o*4+k]*m + a;
    }
  }
  __syncthreads();

  // ---- phase 3: T-mix (rows <CI) || stage A -> act[AOFF] || cw^T -> S[0,RWN)
  for (int idx = tid; idx < CI * 11; idx += 512) {
    int v2 = idx % 11, c = idx / 11;
    float* base = act + c * 220 + v2 * 2;
    float xin[10][2];
    #pragma unroll
    for (int t = 0; t < 10; ++t) { xin[t][0] = base[t*22]; xin[t][1] = base[t*22+1]; }
    float ya[10][2];
    #pragma unroll
    for (int q = 0; q < 10; ++q) { ya[q][0] = 0.f; ya[q][1] = 0.f; }
    #pragma unroll
    for (int t = 0; t < 10; ++t) {
      const float* tm = S + RWN + t * 220 + v2 * 2;
      #pragma unroll
      for (int q = 0; q < 10; ++q) {
        ya[q][0] += tm[q*22]   * xin[t][0];
        ya[q][1] += tm[q*22+1] * xin[t][1];
      }
    }
    #pragma unroll
    for (int q = 0; q < 10; ++q) { base[q*22] = ya[q][0]; base[q*22+1] = ya[q][1]; }
  }
  for (int i = tid; i < 4840; i += 512) act[AOFF + i] = AL[i];
  for (int i = tid; i < RWN; i += 512) {
    int c = i / COP8, o = i % COP8;
    S[i] = (o < CO) ? cw[o * CI + c] : 0.f;
  }
  __syncthreads();

  // ---- phase 4: Sp-mix, in place (A from act[AOFF]) ----
  for (int idx = tid; idx < CI * 10; idx += 512) {
    int t = idx % 10, c = idx / 10;
    float* row = act + c * 220 + t * 22;
    float yin[22];
    #pragma unroll
    for (int v = 0; v < 22; ++v) yin[v] = row[v];
    float za[22];
    #pragma unroll
    for (int w = 0; w < 22; ++w) za[w] = 0.f;
    #pragma unroll 2
    for (int v = 0; v < 22; ++v) {
      const float* ar = act + AOFF + (t * 22 + v) * 22;
      float y0 = yin[v];
      #pragma unroll
      for (int w = 0; w < 22; ++w) za[w] += y0 * ar[w];
    }
    #pragma unroll
    for (int w = 0; w < 22; ++w) row[w] = za[w];
  }
  __syncthreads();

  // ---- phase 5: C-mix -> registers (cw from S) ----
  float cacc[OGRAN * 4];
  if (tid < NT) {
    #pragma unroll
    for (int k = 0; k < OGRAN * 4; ++k) cacc[k] = 0.f;
    #pragma unroll 4
    for (int c = 0; c < CI; ++c) {
      const float* wr = S + c * COP8 + og * OGRAN;
      float4 av = *(const float4*)(act + c * 220 + pp * 4);
      float wv[OGRAN];
      if constexpr (OGRAN == 8) {
        float4 w0 = *(const float4*)(wr);
        float4 w1 = *(const float4*)(wr + 4);
        wv[0]=w0.x; wv[1]=w0.y; wv[2]=w0.z; wv[3]=w0.w;
        wv[4]=w1.x; wv[5]=w1.y; wv[6]=w1.z; wv[7]=w1.w;
      } else if constexpr (OGRAN == 4) {
        float4 w0 = *(const float4*)(wr);
        wv[0]=w0.x; wv[1]=w0.y; wv[2]=w0.z; wv[3]=w0.w;
      } else {
        wv[0] = wr[0];
      }
      #pragma unroll
      for (int o = 0; o < OGRAN; ++o) {
        cacc[o*4+0] += wv[o]*av.x; cacc[o*4+1] += wv[o]*av.y;
        cacc[o*4+2] += wv[o]*av.z; cacc[o*4+3] += wv[o]*av.w;
      }
    }
  }
  __syncthreads();
  // ---- phase 6: write ----
  if (tid < NT) {
    #pragma unroll
    for (int o = 0; o < OGRAN; ++o) {
      float m = cmul[og * OGRAN + o], a = cadd[og * OGRAN + o];
      #pragma unroll
      for (int k = 0; k < 4; ++k) {
        float y = cacc[o*4+k]*m + a + racc[o*4+k];
        act[(og*OGRAN+o)*220 + pp*4 + k] = (y >= 0.f) ? y : preL * y;
      }
    }
  }
  __syncthreads();
}

// Reordered layer (channel mixes FIRST, then T/Sp on CO channels).
// AOFF >= 0: stage A into free act rows during T-phase (L4). AOFF < 0:
// act fully occupied (L2) -- separate A phase in S as before.
template<int CI, int CO, int OGRAN, int AOFF>
DEV void gcn_reord(int tid,
    const float* __restrict__ cw, const float* __restrict__ cb,
    const float* __restrict__ gg, const float* __restrict__ bt,
    const float* __restrict__ rw, const float* __restrict__ rb,
    const float* __restrict__ rg, const float* __restrict__ rbt,
    const float* __restrict__ TmL, const float* __restrict__ AL, float preL,
    float* __restrict__ act, float* __restrict__ S,
    float* __restrict__ rmul, float* __restrict__ radd,
    float* __restrict__ cmul, float* __restrict__ cadd)
{
  constexpr int CO2 = 2 * CO;
  constexpr int COP8 = (CO2 + 7) & ~7;
  constexpr int NT = (CO2 / OGRAN) * 55;
  constexpr int RWN = CI * COP8;
  static_assert(RWN <= 4840, "W2 must fit in S");
  static_assert(AOFF < 0 || AOFF + 4840 <= 14080, "A must fit in act");
  const float inv = 0.99999499987f;

  for (int idx = tid; idx < RWN; idx += 512) {
    int c = idx / COP8, o = idx % COP8;
    float w = 0.f;
    if (o < CO) w = cw[o * CI + c];
    else if (o < CO2) w = rw[(o - CO) * CI + c];
    S[idx] = w;
  }
  for (int idx = tid; idx < 64; idx += 512) {
    bool ok = idx < CO;
    float rm = ok ? rg[idx] * inv : 0.f;
    float cm = ok ? gg[idx] * inv : 0.f;
    rmul[idx] = rm;
    radd[idx] = ok ? rb[idx] * rm + rbt[idx] : 0.f;
    cmul[idx] = cm;
    cadd[idx] = ok ? cb[idx] * cm + bt[idx] : 0.f;
  }
  __syncthreads();

  float acc[OGRAN * 4];
  const int og = tid / 55, pp = tid % 55;
  if (tid < NT) {
    #pragma unroll
    for (int k = 0; k < OGRAN * 4; ++k) acc[k] = 0.f;
    #pragma unroll 4
    for (int c = 0; c < CI; ++c) {
      const float* wr = S + c * COP8 + og * OGRAN;
      float4 av = *(const float4*)(act + c * 220 + pp * 4);
      float wv[OGRAN];
      if constexpr (OGRAN == 8) {
        float4 w0 = *(const float4*)(wr);
        float4 w1 = *(const float4*)(wr + 4);
        wv[0]=w0.x; wv[1]=w0.y; wv[2]=w0.z; wv[3]=w0.w;
        wv[4]=w1.x; wv[5]=w1.y; wv[6]=w1.z; wv[7]=w1.w;
      } else if constexpr (OGRAN == 4) {
        float4 w0 = *(const float4*)(wr);
        wv[0]=w0.x; wv[1]=w0.y; wv[2]=w0.z; wv[3]=w0.w;
      } else {
        wv[0] = wr[0];
      }
      #pragma unroll
      for (int o = 0; o < OGRAN; ++o) {
        acc[o*4+0] += wv[o]*av.x; acc[o*4+1] += wv[o]*av.y;
        acc[o*4+2] += wv[o]*av.z; acc[o*4+3] += wv[o]*av.w;
      }
    }
  }
  __syncthreads();

  if (tid < NT) {
    #pragma unroll
    for (int o = 0; o < OGRAN; ++o) {
      const int oo = og * OGRAN + o;
      const bool isr = oo >= CO;
      const float m = isr ? rmul[oo - CO] : 1.f;
      const float a = isr ? radd[oo - CO] : 0.f;
      #pragma unroll
      for (int k = 0; k < 4; ++k)
        act[oo * 220 + pp * 4 + k] = acc[o*4+k] * m + a;
    }
  }
  for (int i = tid; i < 2200; i += 512) {
    int tq = i / 22, v = i % 22;
    S[i] = TmL[v * 100 + tq];
  }
  __syncthreads();

  // ---- T-mix on u rows || (AOFF>=0) stage A -> act[AOFF] ----
  for (int idx = tid; idx < CO * 11; idx += 512) {
    int v2 = idx % 11, c = idx / 11;
    float* base = act + c * 220 + v2 * 2;
    float xin[10][2];
    #pragma unroll
    for (int t = 0; t < 10; ++t) { xin[t][0] = base[t*22]; xin[t][1] = base[t*22+1]; }
    float ya[10][2];
    #pragma unroll
    for (int q = 0; q < 10; ++q) { ya[q][0] = 0.f; ya[q][1] = 0.f; }
    #pragma unroll
    for (int t = 0; t < 10; ++t) {
      const float* tm = S + t * 220 + v2 * 2;
      #pragma unroll
      for (int q = 0; q < 10; ++q) {
        ya[q][0] += tm[q*22]   * xin[t][0];
        ya[q][1] += tm[q*22+1] * xin[t][1];
      }
    }
    #pragma unroll
    for (int q = 0; q < 10; ++q) { base[q*22] = ya[q][0]; base[q*22+1] = ya[q][1]; }
  }
  if constexpr (AOFF >= 0) {
    for (int i = tid; i < 4840; i += 512) act[AOFF + i] = AL[i];
  }
  __syncthreads();

  if constexpr (AOFF < 0) {
    for (int idx = tid; idx < 4840; idx += 512) S[idx] = AL[idx];
    __syncthreads();
  }

  // ---- Sp-mix on u rows ----
  {
    const float* Abase = (AOFF >= 0) ? (act + AOFF) : S;
    for (int idx = tid; idx < CO * 10; idx += 512) {
      int t = idx % 10, c = idx / 10;
      float* row = act + c * 220 + t * 22;
      float yin[22];
      #pragma unroll
      for (int v = 0; v < 22; ++v) yin[v] = row[v];
      float za[22];
      #pragma unroll
      for (int w = 0; w < 22; ++w) za[w] = 0.f;
      #pragma unroll 2
      for (int v = 0; v < 22; ++v) {
        const float* ar = Abase + (t * 22 + v) * 22;
        float y0 = yin[v];
        #pragma unroll
        for (int w = 0; w < 22; ++w) za[w] += y0 * ar[w];
      }
      #pragma unroll
      for (int w = 0; w < 22; ++w) row[w] = za[w];
    }
  }
  __syncthreads();

  for (int idx = tid; idx < CO * 220; idx += 512) {
    int o = idx / 220, p = idx % 220;
    float y = act[o * 220 + p] * cmul[o] + cadd[o] + act[(CO + o) * 220 + p];
    act[o * 220 + p] = (y >= 0.f) ? y : preL * y;
  }
  __syncthreads();
}

__global__ __launch_bounds__(512, 4)
void enc_kernel(const float* __restrict__ x, const float* __restrict__ A,
                const float* __restrict__ Tm, const float* __restrict__ pre, EncW W,
                const float* __restrict__ qkvT, const float* __restrict__ qkv_b,
                float* __restrict__ h0_ws, float* __restrict__ k_ws,
                float* __restrict__ v_ws)
{
  __shared__ __align__(16) float act[64 * 220];   // 56320 B
  __shared__ __align__(16) float S[4840];         // 19360 B (W/Tm/A mux)
  __shared__ float rmul[64], radd[64], cmul[64], cadd[64];  // 1024 B

  const int tid = threadIdx.x;
  const int b = blockIdx.x;

  for (int idx = tid; idx < 660; idx += 512) {
    int c = idx / 220, r = idx % 220, t = r / 22, v = r % 22;
    act[c * 220 + t * 22 + v] = x[(((size_t)b * 10 + t) * 22 + v) * 3 + c];
  }
  float p0 = pre[0], p1 = pre[1], p2 = pre[2], p3 = pre[3];

  gcn_l1_fused(tid, W.cw[0], W.cb[0], W.g[0], W.bt[0], W.rw[0], W.rb[0], W.rg[0], W.rbt[0],
               Tm, A, p0, act, S, cadd);
  gcn_reord<64, 32, 8, -1>(tid, W.cw[1], W.cb[1], W.g[1], W.bt[1], W.rw[1], W.rb[1], W.rg[1], W.rbt[1],
                     Tm + 2200, A + 4840, p1, act, S, rmul, radd, cmul, cadd);
  gcn_orig<32, 64, 8>(tid, W.cw[2], W.cb[2], W.g[2], W.bt[2], W.rw[2], W.rb[2], W.rg[2], W.rbt[2],
                     Tm + 4400, A + 9680, p2, act, S, rmul, radd, cmul, cadd);
  gcn_reord<64, 3, 1, 6 * 220>(tid, W.cw[3], W.cb[3], W.g[3], W.bt[3], W.rw[3], W.rb[3], W.rg[3], W.rbt[3],
                     Tm + 6600, A + 14520, p3, act, S, rmul, radd, cmul, cadd);

  float* encD = act + 3 * 220;
  for (int idx = tid; idx < 660; idx += 512) {
    int t = idx / 66, d = idx % 66, v = d / 3, c = d % 3;
    float val = act[c * 220 + t * 22 + v];
    encD[idx] = val;
    if (t == 9) h0_ws[(size_t)b * 66 + d] = val;
  }
  __syncthreads();

  for (int idx = tid; idx < 1320; idx += 512) {
    const int t = idx / 132, dd = idx % 132;
    const int row = 66 + dd;
    const float* wp = qkvT + row;        // qkvT[e*198+row]
    const float* ep = encD + t * 66;
    float acc = 0.f;
    #pragma unroll 6
    for (int e = 0; e < 66; ++e) acc += wp[e * 198] * ep[e];
    acc += qkv_b[row];
    const int half = dd / 66, d = dd - half * 66;
    float* dst = half ? v_ws : k_ws;
    dst[(size_t)b * 660 + t * 66 + d] = acc;
  }
}

// ------------------------- prep: transposes + folds (all f32) ---------------

__global__ __launch_bounds__(512)
void prep_kernel(const float* __restrict__ qkv_w, const float* __restrict__ ow,
                 const float* __restrict__ ob, const float* __restrict__ lw,
                 const float* __restrict__ gru_wi, const float* __restrict__ gru_wh,
                 float* __restrict__ qkvT, float* __restrict__ wqD,
                 float* __restrict__ lwAT, float* __restrict__ MT,
                 float* __restrict__ cb2, float* __restrict__ wT_g)
{
  int idx = blockIdx.x * 512 + threadIdx.x;
  if (idx < 13068) {                 // qkvT[e*198+j] = qkv_w[j*66+e]
    int e = idx / 198, j = idx % 198;
    qkvT[idx] = qkv_w[j * 66 + e];
    return;
  }
  int i1 = idx - 13068;
  if (i1 < 4356) {                   // wqD[e*66+d] = qkv_w[d*66+e]
    int e = i1 / 66, d = i1 % 66;
    wqD[i1] = qkv_w[d * 66 + e];
    return;
  }
  int i2 = i1 - 4356;
  if (i2 < 4356) {                   // lwAT[e*66+d] = lw[d*132+e]
    int e = i2 / 66, d = i2 % 66;
    lwAT[i2] = lw[d * 132 + e];
    return;
  }
  int i3 = i2 - 4356;
  if (i3 < 4356) {                   // MT[e*66+d] = sum_f lwB[d][f]*ow[f][e]
    int e = i3 / 66, d = i3 % 66;
    const float* lrow = lw + d * 132 + 66;
    float acc = 0.f;
    for (int f = 0; f < 66; ++f) acc += lrow[f] * ow[f * 66 + e];
    MT[i3] = acc;
    return;
  }
  int i4 = i3 - 4356;
  if (i4 < 66) {                     // cb2[d] = lwB[d] @ ob
    const float* lrow = lw + i4 * 132 + 66;
    float acc = 0.f;
    for (int f = 0; f < 66; ++f) acc += lrow[f] * ob[f];
    cb2[i4] = acc;
    return;
  }
  int i5 = i4 - 66;
  if (i5 < 26136) {                  // wT_g[e*396+jm]: jm<198 wi, else wh
    int e = i5 / 396, jm = i5 % 396;
    wT_g[i5] = (jm < 198) ? gru_wi[jm * 66 + e] : gru_wh[(jm - 198) * 66 + e];
  }
}

// ---------------------------------------------------------------- decoder ---
// EXACT R10 champion decoder (~300us, FETCH ~7MB). Session rules: keep short
// unrolls (11), scalar weight loads, <=~40 live floats per thread -- all
// MLP-widening restructures spill at the allocator's fixed 64-VGPR target
// (R6/R9/R11). R3: don't shrink R. R9: don't stream lwAT/MT per-step.

__global__ __launch_bounds__(512, 4)
void dec_kernel(const float* __restrict__ x, const float* __restrict__ h0_ws,
                const float* __restrict__ k_ws, const float* __restrict__ v_ws,
                const float* __restrict__ wT_g,
                const float* __restrict__ gru_bi, const float* __restrict__ gru_bh,
                const float* __restrict__ wqD, const float* __restrict__ qkv_b,
                const float* __restrict__ lwAT, const float* __restrict__ MT,
                const float* __restrict__ cb2, const float* __restrict__ lb,
                float* __restrict__ outp)
{
  __shared__ __align__(16) float kpS[7920];      // 31680 B  (r,h,t) x e
  __shared__ __align__(16) float lwAS[4356];     // 17424 B
  __shared__ __align__(16) float MS[4356];       // 17424 B
  __shared__ __align__(16) float G[396 * 4];     //  6336 B
  __shared__ __align__(16) float tpT[264], hsT[264], cxT[264];  // 3168 B
  __shared__ float attnS[120];                   //   480 B (raw scores)
  __shared__ float kbS[120];                     //   480 B
  __shared__ float biS[198], bhS[198], lbS[66];  //  1848 B
  // total ~78.9 KB -> 2 blocks/CU

  const int tid = threadIdx.x;
  const int b0 = blockIdx.x * 4;
  const float qscale = 1.0f / sqrtf(22.0f);

  for (int idx = tid; idx < 4356; idx += 512) {
    lwAS[idx] = lwAT[idx]; MS[idx] = MT[idx];
  }
  for (int idx = tid; idx < 198; idx += 512) { biS[idx] = gru_bi[idx]; bhS[idx] = gru_bh[idx]; }
  for (int idx = tid; idx < 66; idx += 512)  { lbS[idx] = lb[idx] + cb2[idx]; }
  for (int idx = tid; idx < 264; idx += 512) {
    int d = idx >> 2, r = idx & 3;
    hsT[d * 4 + r] = h0_ws[(size_t)(b0 + r) * 66 + d];
    tpT[d * 4 + r] = x[(size_t)(b0 + r) * 660 + 594 + d];
  }
  // kp precompute: kp[r,h,t,e] = scale*sum_j wq[h*22+j,e]*k[r,t,h*22+j]
  for (int idx = tid; idx < 7920; idx += 512) {
    const int g = idx / 66, e = idx % 66;
    const int r = g / 30, rem = g % 30, h = rem / 10, t = rem % 10;
    const float* wq = wqD + e * 66 + h * 22;
    const float* kv = k_ws + (size_t)(b0 + r) * 660 + t * 66 + h * 22;
    float acc = 0.f;
    #pragma unroll
    for (int j = 0; j < 22; ++j) acc += wq[j] * kv[j];
    kpS[idx] = acc * qscale;
  }
  for (int idx = tid; idx < 120; idx += 512) {
    const int r = idx / 30, rem = idx % 30, h = rem / 10, t = rem % 10;
    const float* kv = k_ws + (size_t)(b0 + r) * 660 + t * 66 + h * 22;
    float acc = 0.f;
    #pragma unroll
    for (int j = 0; j < 22; ++j) acc += qkv_b[h * 22 + j] * kv[j];
    kbS[idx] = acc * qscale;
  }
  __syncthreads();

  for (int s = 0; s < 25; ++s) {
    // P1: G[jm] = act @ w_jm + bias; 198 threads x 2 columns sharing one
    // activation stream. tid<99: wi cols (tid, tid+99), src tpT.
    // tid in [99,198): wh cols (tid+99, tid+198), src hsT.
    if (tid < 198) {
      const bool lo = tid < 99;
      const int j0 = lo ? tid : (tid + 99);
      const int j1 = j0 + 99;
      const float* base = lo ? tpT : hsT;
      const float* w0 = wT_g + j0;
      const float* w1 = wT_g + j1;
      float a0 = 0.f, a1 = 0.f, a2 = 0.f, a3 = 0.f;
      float c0 = 0.f, c1 = 0.f, c2 = 0.f, c3 = 0.f;
      #pragma unroll 11
      for (int e = 0; e < 66; ++e) {
        float4 av = *(const float4*)(base + e * 4);
        const float wa = w0[e * 396];
        const float wb = w1[e * 396];
        a0 += wa * av.x; a1 += wa * av.y; a2 += wa * av.z; a3 += wa * av.w;
        c0 += wb * av.x; c1 += wb * av.y; c2 += wb * av.z; c3 += wb * av.w;
      }
      const float bias0 = lo ? biS[j0] : bhS[j0 - 198];
      const float bias1 = lo ? biS[j1] : bhS[j1 - 198];
      *(float4*)(G + j0 * 4) = make_float4(a0 + bias0, a1 + bias0, a2 + bias0, a3 + bias0);
      *(float4*)(G + j1 * 4) = make_float4(c0 + bias1, c1 + bias1, c2 + bias1, c3 + bias1);
    }
    __syncthreads();

    // P2: GRU gates -> hs
    if (tid < 264) {
      int d = tid >> 2, r = tid & 3;
      float ir = G[d * 4 + r]         + G[(198 + d) * 4 + r];
      float iz = G[(66 + d) * 4 + r]  + G[(264 + d) * 4 + r];
      float nx = G[(132 + d) * 4 + r];
      float hn = G[(330 + d) * 4 + r];
      float rg = 1.f / (1.f + __expf(-ir));
      float zg = 1.f / (1.f + __expf(-iz));
      float t2 = __expf(2.f * (nx + rg * hn));
      float ng = 1.f - 2.f / (t2 + 1.f);        // tanh, overflow-safe
      float h = hsT[d * 4 + r];
      hsT[d * 4 + r] = (1.f - zg) * ng + zg * h;
    }
    __syncthreads();

    // P4a: raw scores via kp (480 lanes: 4-way e-split + shfl combine)
    if (tid < 480) {
      const int g = tid >> 2, q4 = tid & 3;
      const int r = g / 30;
      const int e0 = q4 * 17;
      const int e1 = (q4 == 3) ? 66 : e0 + 17;
      const float* kpr = kpS + g * 66;
      float acc = 0.f;
      for (int e = e0; e < e1; ++e) acc += hsT[e * 4 + r] * kpr[e];
      acc += __shfl_xor(acc, 1);
      acc += __shfl_xor(acc, 2);
      if (q4 == 0) attnS[g] = acc + kbS[g];
    }
    __syncthreads();

    // P5: per-thread softmax + ctx = (sum p*v)/sum p (v from global, L2-hot)
    if (tid < 264) {
      int r = tid / 66, d = tid % 66, h = d / 22;
      const float* sp = attnS + (r * 3 + h) * 10;
      float sc[10];
      float mx = sp[0];
      #pragma unroll
      for (int t = 1; t < 10; ++t) { sc[t] = sp[t]; mx = fmaxf(mx, sp[t]); }
      sc[0] = sp[0];
      float sum = 0.f;
      #pragma unroll
      for (int t = 0; t < 10; ++t) { float e = __expf(sc[t] - mx); sc[t] = e; sum += e; }
      const float* vp = v_ws + (size_t)(b0 + r) * 660 + d;
      float acc = 0.f;
      #pragma unroll
      for (int t = 0; t < 10; ++t) acc += sc[t] * vp[t * 66];
      cxT[d * 4 + r] = acc / sum;
    }
    __syncthreads();

    // P7: thread (d, q=tid&3) computes partials for ALL 4 rows over e-chunk
    // q (4 LDS insts / 4 outputs); 4-lane shfl_xor combine; thread q keeps r=q.
    if (tid < 264) {
      const int d = tid >> 2, q = tid & 3;
      const int e0 = q * 17;
      const int e1 = (q == 3) ? 66 : e0 + 17;
      float x0 = 0.f, x1 = 0.f, x2 = 0.f, x3 = 0.f;
      for (int e = e0; e < e1; ++e) {
        const float wa = lwAS[e * 66 + d];
        const float wm = MS[e * 66 + d];
        const float4 hv = *(const float4*)(hsT + e * 4);
        const float4 cv = *(const float4*)(cxT + e * 4);
        x0 += wa * hv.x + wm * cv.x;
        x1 += wa * hv.y + wm * cv.y;
        x2 += wa * hv.z + wm * cv.z;
        x3 += wa * hv.w + wm * cv.w;
      }
      x0 += __shfl_xor(x0, 1); x0 += __shfl_xor(x0, 2);
      x1 += __shfl_xor(x1, 1); x1 += __shfl_xor(x1, 2);
      x2 += __shfl_xor(x2, 1); x2 += __shfl_xor(x2, 2);
      x3 += __shfl_xor(x3, 1); x3 += __shfl_xor(x3, 2);
      const float val = (q == 0) ? x0 : (q == 1) ? x1 : (q == 2) ? x2 : x3;
      const float pred = val + lbS[d] + tpT[d * 4 + q];
      outp[((size_t)(b0 + q) * 25 + s) * 66 + d] = pred;
      tpT[d * 4 + q] = pred;
    }
    __syncthreads();
  }
}

// ----------------------------------------------------------------- launch ---

extern "C" void kernel_launch(void* const* d_in, const int* in_sizes, int n_in,
                              void* d_out, int out_size, void* d_ws, size_t ws_size,
                              hipStream_t stream) {
  (void)in_sizes; (void)n_in; (void)out_size; (void)ws_size;
  const float* x   = (const float*)d_in[0];
  const float* A   = (const float*)d_in[1];
  const float* Tm  = (const float*)d_in[2];
  const float* pre = (const float*)d_in[3];
  EncW W;
  for (int i = 0; i < 4; ++i) {
    W.cw[i]  = (const float*)d_in[4 + 8 * i + 0];
    W.cb[i]  = (const float*)d_in[4 + 8 * i + 1];
    W.g[i]   = (const float*)d_in[4 + 8 * i + 2];
    W.bt[i]  = (const float*)d_in[4 + 8 * i + 3];
    W.rw[i]  = (const float*)d_in[4 + 8 * i + 4];
    W.rb[i]  = (const float*)d_in[4 + 8 * i + 5];
    W.rg[i]  = (const float*)d_in[4 + 8 * i + 6];
    W.rbt[i] = (const float*)d_in[4 + 8 * i + 7];
  }
  const float* gru_wi = (const float*)d_in[36];
  const float* gru_wh = (const float*)d_in[37];
  const float* gru_bi = (const float*)d_in[38];
  const float* gru_bh = (const float*)d_in[39];
  const float* qkv_w  = (const float*)d_in[40];
  const float* qkv_b  = (const float*)d_in[41];
  const float* ow     = (const float*)d_in[42];
  const float* ob     = (const float*)d_in[43];
  const float* lw     = (const float*)d_in[44];
  const float* lb     = (const float*)d_in[45];

  float* wsf  = (float*)d_ws;
  float* h0   = wsf;                       // 2048*66
  float* kw   = h0 + 2048 * 66;            // 2048*660
  float* vw   = kw + 2048 * 660;           // 2048*660
  float* qkvT = vw + 2048 * 660;           // 13068
  float* wqD  = qkvT + 13068;              // 4356
  float* lwAT = wqD + 4356;                // 4356
  float* MT   = lwAT + 4356;               // 4356
  float* cb2  = MT + 4356;                 // 66
  float* wT_g = cb2 + 66;                  // 26136

  prep_kernel<<<103, 512, 0, stream>>>(qkv_w, ow, ob, lw, gru_wi, gru_wh,
                                       qkvT, wqD, lwAT, MT, cb2, wT_g);
  enc_kernel<<<2048, 512, 0, stream>>>(x, A, Tm, pre, W, qkvT, qkv_b, h0, kw, vw);
  dec_kernel<<<512, 512, 0, stream>>>(x, h0, kw, vw, wT_g, gru_bi, gru_bh,
                                      wqD, qkv_b, lwAT, MT, cb2, lb,
                                      (float*)d_out);
}